// Round 7
// baseline (339.358 us; speedup 1.0000x reference)
//
#include <hip/hip_runtime.h>

#define H 2048
#define HH (H * H)
#define NIDX 2097152
#define BINS 256
#define CH 3

// ---------------- main-path ws layout ----------------
#define WS_HIST_DST 0
#define WS_HIST_REF 3072
#define WS_TABLE    6144
#define WS_ACC      9216
#define WS_DONE_G   10240                       // uint ticket (gather)
#define WS_DONE_L   10244                       // uint ticket (loss)
#define WS_CTRL_BYTES 16384
#define WS_SEL      16384                       // uchar[HH]
// memset covers ctrl + sel contiguously:
#define WS_ZERO_BYTES (16384 + (size_t)HH)
#define WS_BPS      (16384 + (size_t)HH)        // uint[HH] binpack_src
#define WS_BPR      (WS_BPS + (size_t)HH * 4)   // uint[HH] binpack_ref
#define WS_PD       (WS_BPR + (size_t)HH * 4)   // uint[NIDX] packed dst pos
#define WS_PR       (WS_PD + (size_t)NIDX * 4)  // uint[NIDX] packed ref pos
#define WS_MAIN_BYTES (WS_PR + (size_t)NIDX * 4)

// ---------------- fallback ws layout ----------------
#define FB_CNT_DST  16384
#define FB_BINPACK  (16384 + (size_t)HH * 2)
#define FB_ZERO_BYTES (16384 + (size_t)HH * 2)

__device__ __forceinline__ int bin_of(float v) {
    int b = (int)floorf(v);
    return min(max(b, 0), BINS - 1);
}

// ============================================================
// MAIN PATH (R7: partition ELIMINATED)
// ============================================================
// R2-R6 showed prep_part pinned at 76-84us across 4 prep layouts and 2
// partition configs, with SQ_LDS_BANK_CONFLICT invariant at ~815K: the
// partition's 8M contended LDS atomic ops are a per-CU-constant floor.
// R7 removes it: buckets become the 8 XCD-sized slices (p>>19, 2MB of
// binpack each). Kernel1 = prep (streaming, no LDS) + pack (pd/pr pos
// arrays, no LDS). Kernel2 = scan_gather: each XCD scans the full pd/pr
// stream (L3-resident) and gathers only its own slice -> L2-local, no
// lists, no LDS atomics outside the 768-bin histograms.
// R3/R4 lesson kept: NO __threadfence() per block (L2 flush storm);
// tickets use device-scope atomics + __syncthreads drain only (R5-validated).

#define PACK_BLOCKS 256
#define PREP_BLOCKS 1024
#define PQ (HH / 4 / 4)             // 262144: prep far-split q-slice stride
#define GRID1 (PACK_BLOCKS + PREP_BLOCKS)

__global__ __launch_bounds__(256) void prep_pack_kernel(
    const float* __restrict__ mask_src, const float* __restrict__ mask_tar,
    const float* __restrict__ refimg, const float* __restrict__ tgtimg,
    unsigned int* __restrict__ bps, unsigned int* __restrict__ bpr,
    const int* __restrict__ idx0, const int* __restrict__ idx1,
    const int* __restrict__ idx2, const int* __restrict__ idx3,
    unsigned int* __restrict__ pd, unsigned int* __restrict__ pr)
{
    if (blockIdx.x < PACK_BLOCKS) {
        // ---- pack: 8192 samples/block, int4 loads, uint4 stores ----
        const int base4 = blockIdx.x * 2048;   // uint4 groups
        #pragma unroll
        for (int r = 0; r < 8; ++r) {
            int k4 = base4 + r * 256 + threadIdx.x;
            int4 a = ((const int4*)idx0)[k4];
            int4 b = ((const int4*)idx1)[k4];
            int4 c = ((const int4*)idx2)[k4];
            int4 d = ((const int4*)idx3)[k4];
            uint4 opd = { (unsigned int)(a.x * H + b.x), (unsigned int)(a.y * H + b.y),
                          (unsigned int)(a.z * H + b.z), (unsigned int)(a.w * H + b.w) };
            uint4 opr = { (unsigned int)(c.x * H + d.x), (unsigned int)(c.y * H + d.y),
                          (unsigned int)(c.z * H + d.z), (unsigned int)(c.w * H + d.w) };
            ((uint4*)pd)[k4] = opd;
            ((uint4*)pr)[k4] = opr;
        }
    } else {
        // ---- prep: far-split 4-way, fully coalesced (R6) ----
        const int t = (int)(blockIdx.x - PACK_BLOCKS) * 256 + threadIdx.x; // 0..262143
        float4 msv[4], mtv[4];
        #pragma unroll
        for (int k = 0; k < 4; ++k) {
            msv[k] = ((const float4*)mask_src)[t + k * PQ];
            mtv[k] = ((const float4*)mask_tar)[t + k * PQ];
        }
        unsigned int wsrc[4][4] = {{0u,0u,0u,0u},{0u,0u,0u,0u},{0u,0u,0u,0u},{0u,0u,0u,0u}};
        unsigned int wref[4][4] = {{0u,0u,0u,0u},{0u,0u,0u,0u},{0u,0u,0u,0u},{0u,0u,0u,0u}};
        #pragma unroll
        for (int c = 0; c < CH; ++c) {
            float4 rv[4], tv[4];
            #pragma unroll
            for (int k = 0; k < 4; ++k) {
                rv[k] = ((const float4*)(refimg + (size_t)c * HH))[t + k * PQ];
                tv[k] = ((const float4*)(tgtimg + (size_t)c * HH))[t + k * PQ];
            }
            #pragma unroll
            for (int k = 0; k < 4; ++k) {
                const float* rr = &rv[k].x;
                const float* tt = &tv[k].x;
                const float* mm = &msv[k].x;
                const float* mt2 = &mtv[k].x;
                #pragma unroll
                for (int e = 0; e < 4; ++e) {
                    float vs = (rr[e] * 0.5f + 0.5f) * 255.0f * mm[e];
                    float vt = (tt[e] * 0.5f + 0.5f) * 255.0f * mt2[e];
                    wsrc[k][e] |= ((unsigned int)bin_of(vs)) << (8 * c);
                    wref[k][e] |= ((unsigned int)bin_of(vt)) << (8 * c);
                }
            }
        }
        #pragma unroll
        for (int k = 0; k < 4; ++k) {
            uint4 os = { wsrc[k][0], wsrc[k][1], wsrc[k][2], wsrc[k][3] };
            uint4 orf = { wref[k][0], wref[k][1], wref[k][2], wref[k][3] };
            ((uint4*)bps)[t + k * PQ] = os;
            ((uint4*)bpr)[t + k * PQ] = orf;
        }
    }
}

// Scan-gather: 1024 blocks = 8 xcd x 128 slots. Block (xcd, slot) scans
// samples [slot*16384, (slot+1)*16384) of BOTH sides and processes only
// positions in its XCD's 2MB slice (p>>19 == xcd). Random reads confined
// per-XCD; pd/pr streams are L3-resident. Fence-free table tail (R5).
#define SG_BLOCKS 1024
__global__ __launch_bounds__(256) void scan_gather_kernel(
    const unsigned int* __restrict__ pd, const unsigned int* __restrict__ pr,
    const unsigned int* __restrict__ bps, const unsigned int* __restrict__ bpr,
    unsigned char* __restrict__ selected,
    unsigned int* __restrict__ hist_dst, unsigned int* __restrict__ hist_ref,
    int* __restrict__ table, unsigned int* __restrict__ done)
{
    __shared__ unsigned int hd[CH * BINS];
    __shared__ unsigned int hr[CH * BINS];
    for (int i = threadIdx.x; i < CH * BINS; i += 256) { hd[i] = 0u; hr[i] = 0u; }
    __syncthreads();

    const unsigned int xcd = (unsigned int)(blockIdx.x & 7);
    const int slot = blockIdx.x >> 3;        // 0..127
    const int base4 = slot * 4096;           // 16384 samples / 4 per block

    unsigned int zc_d = 0, zc_r = 0;
    for (int r = 0; r < 16; ++r) {
        int k4 = base4 + r * 256 + threadIdx.x;
        uint4 pdv = ((const uint4*)pd)[k4];
        uint4 prv = ((const uint4*)pr)[k4];
        const unsigned int PD[4] = { pdv.x, pdv.y, pdv.z, pdv.w };
        const unsigned int PR[4] = { prv.x, prv.y, prv.z, prv.w };
        #pragma unroll
        for (int e = 0; e < 4; ++e) {
            unsigned int p = PD[e];
            if ((p >> 19) == xcd) {
                unsigned int w = bps[p];
                selected[p] = 1;
                if (w == 0u) ++zc_d;
                else {
                    atomicAdd(&hd[0 * BINS + (w & 0xFFu)], 1u);
                    atomicAdd(&hd[1 * BINS + ((w >> 8) & 0xFFu)], 1u);
                    atomicAdd(&hd[2 * BINS + ((w >> 16) & 0xFFu)], 1u);
                }
            }
        }
        #pragma unroll
        for (int e = 0; e < 4; ++e) {
            unsigned int p = PR[e];
            if ((p >> 19) == xcd) {
                unsigned int w = bpr[p];
                if (w == 0u) ++zc_r;
                else {
                    atomicAdd(&hr[0 * BINS + (w & 0xFFu)], 1u);
                    atomicAdd(&hr[1 * BINS + ((w >> 8) & 0xFFu)], 1u);
                    atomicAdd(&hr[2 * BINS + ((w >> 16) & 0xFFu)], 1u);
                }
            }
        }
    }

    int zd = (int)zc_d, zr = (int)zc_r;
    #pragma unroll
    for (int off = 32; off; off >>= 1) { zd += __shfl_down(zd, off); zr += __shfl_down(zr, off); }
    if ((threadIdx.x & 63) == 0) {
        if (zd) {
            atomicAdd(&hd[0 * BINS], (unsigned int)zd);
            atomicAdd(&hd[1 * BINS], (unsigned int)zd);
            atomicAdd(&hd[2 * BINS], (unsigned int)zd);
        }
        if (zr) {
            atomicAdd(&hr[0 * BINS], (unsigned int)zr);
            atomicAdd(&hr[1 * BINS], (unsigned int)zr);
            atomicAdd(&hr[2 * BINS], (unsigned int)zr);
        }
    }

    __syncthreads();
    for (int i = threadIdx.x; i < CH * BINS; i += 256) {
        unsigned int v = hd[i];
        if (v) atomicAdd(&hist_dst[i], v);
        v = hr[i];
        if (v) atomicAdd(&hist_ref[i], v);
    }

    // ---- fence-free ticket: last block computes the table ----
    __shared__ int is_last;
    __syncthreads();                      // drains this block's vmem
    if (threadIdx.x == 0) {
        unsigned int t = atomicAdd(done, 1u);   // device-scope
        is_last = (t == gridDim.x - 1u) ? 1 : 0;
    }
    __syncthreads();
    if (!is_last) return;

    __shared__ float cd[CH * BINS];
    __shared__ float cr[CH * BINS];
    __shared__ float wpart[4];
    const int i = threadIdx.x;        // 0..255
    const int lane = i & 63;
    const int wave = i >> 6;

    for (int a = 0; a < 6; ++a) {
        unsigned int* h = (a < 3) ? (hist_dst + a * BINS) : (hist_ref + (a - 3) * BINS);
        float* out = (a < 3) ? (cd + a * BINS) : (cr + (a - 3) * BINS);
        // coherent read of device-scope atomic results: RMW with 0
        float x = (float)atomicAdd(&h[i], 0u);
        #pragma unroll
        for (int off = 1; off < 64; off <<= 1) {
            float y = __shfl_up(x, off);
            if (lane >= off) x += y;
        }
        if (lane == 63) wpart[wave] = x;
        __syncthreads();
        float prefix = 0.0f;
        #pragma unroll
        for (int w = 0; w < 3; ++w) if (w < wave) prefix += wpart[w];
        x += prefix;
        float tot = wpart[0] + wpart[1] + wpart[2] + wpart[3];
        out[i] = x / tot;
        __syncthreads();
    }

    #pragma unroll
    for (int c = 0; c < CH; ++c) {
        int t;
        if (i == 0) t = 0;
        else if (i == BINS - 1) t = BINS - 1;
        else {
            float r = cd[c * BINS + i];
            int lo = 1, hi = BINS - 1;
            while (lo < hi) {
                int mid = (lo + hi) >> 1;
                if (cr[c * BINS + mid] < r) lo = mid + 1; else hi = mid;
            }
            t = (cr[c * BINS + lo - 1] <= r) ? lo : i;
        }
        table[c * BINS + i] = t;
    }
}

// Far-split 4-way loss (grid 1024), fence-free fused finalize (R5/R6).
#define L_BLOCKS 1024
__global__ __launch_bounds__(256) void loss_sel_kernel(
    const float* __restrict__ input, const float* __restrict__ refimg,
    const float* __restrict__ mask_src, const unsigned char* __restrict__ selected,
    const int* __restrict__ table, double* __restrict__ acc,
    float* __restrict__ out_loss, unsigned int* __restrict__ done)
{
    __shared__ int tab[CH * BINS];
    for (int i = threadIdx.x; i < CH * BINS; i += 256) tab[i] = table[i];
    __syncthreads();

    const int t = blockIdx.x * 256 + threadIdx.x;   // 0..262143
    float4 mv[4];
    uchar4 sv[4];
    #pragma unroll
    for (int k = 0; k < 4; ++k) {
        mv[k] = ((const float4*)mask_src)[t + k * PQ];
        sv[k] = ((const uchar4*)selected)[t + k * PQ];
    }

    float lsum = 0.0f;
    #pragma unroll
    for (int c = 0; c < CH; ++c) {
        float4 av4[4], rv4[4];
        #pragma unroll
        for (int k = 0; k < 4; ++k) {
            av4[k] = ((const float4*)(input  + (size_t)c * HH))[t + k * PQ];
            rv4[k] = ((const float4*)(refimg + (size_t)c * HH))[t + k * PQ];
        }
        #pragma unroll
        for (int k = 0; k < 4; ++k) {
            const float* aa = &av4[k].x;
            const float* rr = &rv4[k].x;
            const float* mm = &mv[k].x;
            const unsigned char ss[4] = { sv[k].x, sv[k].y, sv[k].z, sv[k].w };
            #pragma unroll
            for (int e = 0; e < 4; ++e) {
                float m = mm[e];
                float av = (aa[e] * 0.5f + 0.5f) * 255.0f * m;
                float rv = (rr[e] * 0.5f + 0.5f) * 255.0f * m;
                float tv = (float)tab[c * BINS + bin_of(rv)];
                float mvv = m * (ss[e] ? tv : rv);
                lsum += fabsf(av - mvv);
            }
        }
    }

    double d = (double)lsum;
    #pragma unroll
    for (int off = 32; off; off >>= 1) d += __shfl_down(d, off);
    __shared__ double wsum[4];
    int wid = threadIdx.x >> 6;
    int lane = threadIdx.x & 63;
    if (lane == 0) wsum[wid] = d;
    __syncthreads();
    if (threadIdx.x == 0) {
        double tt = wsum[0] + wsum[1] + wsum[2] + wsum[3];
        atomicAdd(acc, tt);
    }

    // ---- fence-free ticket: last block writes the scalar output ----
    __shared__ int is_last;
    __syncthreads();
    if (threadIdx.x == 0) {
        unsigned int tk = atomicAdd(done, 1u);
        is_last = (tk == gridDim.x - 1u) ? 1 : 0;
    }
    __syncthreads();
    if (!is_last) return;
    if (threadIdx.x == 0) {
        double a = atomicAdd(acc, 0.0);   // coherent RMW read
        out_loss[0] = (float)(a / (double)(CH * (double)HH));
    }
}

// Standalone table/finalize kept for the fallback path.
__global__ __launch_bounds__(256) void table_kernel(
    const unsigned int* __restrict__ hist_dst,
    const unsigned int* __restrict__ hist_ref,
    int* __restrict__ table)
{
    __shared__ float cd[CH * BINS];
    __shared__ float cr[CH * BINS];
    __shared__ float wpart[4];
    const int i = threadIdx.x;        // 0..255
    const int lane = i & 63;
    const int wave = i >> 6;

    for (int a = 0; a < 6; ++a) {
        const unsigned int* h = (a < 3) ? (hist_dst + a * BINS) : (hist_ref + (a - 3) * BINS);
        float* out = (a < 3) ? (cd + a * BINS) : (cr + (a - 3) * BINS);
        float x = (float)h[i];
        #pragma unroll
        for (int off = 1; off < 64; off <<= 1) {
            float y = __shfl_up(x, off);
            if (lane >= off) x += y;
        }
        if (lane == 63) wpart[wave] = x;
        __syncthreads();
        float prefix = 0.0f;
        #pragma unroll
        for (int w = 0; w < 3; ++w) if (w < wave) prefix += wpart[w];
        x += prefix;
        float tot = wpart[0] + wpart[1] + wpart[2] + wpart[3];
        out[i] = x / tot;
        __syncthreads();
    }

    #pragma unroll
    for (int c = 0; c < CH; ++c) {
        int t;
        if (i == 0) t = 0;
        else if (i == BINS - 1) t = BINS - 1;
        else {
            float r = cd[c * BINS + i];
            int lo = 1, hi = BINS - 1;
            while (lo < hi) {
                int mid = (lo + hi) >> 1;
                if (cr[c * BINS + mid] < r) lo = mid + 1; else hi = mid;
            }
            t = (cr[c * BINS + lo - 1] <= r) ? lo : i;
        }
        table[c * BINS + i] = t;
    }
}

__global__ void finalize_kernel(const double* __restrict__ acc, float* __restrict__ out)
{
    if (threadIdx.x == 0 && blockIdx.x == 0) {
        out[0] = (float)(acc[0] / (double)(CH * (double)HH));
    }
}

// ============================================================
// FALLBACK PATH (proven pipeline) — used if ws_size too small
// ============================================================

__device__ __forceinline__ void cnt_inc(unsigned int* cnt, int p) {
    atomicAdd(&cnt[p >> 1], (p & 1) ? 0x10000u : 1u);
}

__global__ __launch_bounds__(256) void fb_prep_kernel(
    const float* __restrict__ mask_tar, const float* __restrict__ tgtimg,
    unsigned int* __restrict__ binpack)
{
    const int nq = HH / 4;
    const int stride = gridDim.x * 256;
    for (int q = blockIdx.x * 256 + threadIdx.x; q < nq; q += stride) {
        float4 m4 = ((const float4*)mask_tar)[q];
        const float mm[4] = { m4.x, m4.y, m4.z, m4.w };
        unsigned int w[4] = { 0u, 0u, 0u, 0u };
        #pragma unroll
        for (int c = 0; c < CH; ++c) {
            float4 t4 = ((const float4*)(tgtimg + (size_t)c * HH))[q];
            const float tt[4] = { t4.x, t4.y, t4.z, t4.w };
            #pragma unroll
            for (int e = 0; e < 4; ++e) {
                float v = (tt[e] * 0.5f + 0.5f) * 255.0f * mm[e];
                w[e] |= ((unsigned int)bin_of(v)) << (8 * c);
            }
        }
        uint4 out = { w[0], w[1], w[2], w[3] };
        ((uint4*)binpack)[q] = out;
    }
}

__global__ __launch_bounds__(256) void fb_scatter_kernel(
    const int4* __restrict__ idx0, const int4* __restrict__ idx1,
    const int4* __restrict__ idx2, const int4* __restrict__ idx3,
    const unsigned int* __restrict__ binpack,
    unsigned int* __restrict__ cnt_dst, unsigned int* __restrict__ hist_ref)
{
    __shared__ unsigned int hr[CH * BINS];
    for (int i = threadIdx.x; i < CH * BINS; i += 256) hr[i] = 0u;
    __syncthreads();

    unsigned int zc = 0;
    const int n4 = NIDX / 4;
    const int stride = gridDim.x * 256;
    for (int k = blockIdx.x * 256 + threadIdx.x; k < n4; k += stride) {
        int4 a = idx0[k], b = idx1[k], c = idx2[k], d = idx3[k];
        int p0 = c.x * H + d.x, p1 = c.y * H + d.y;
        int p2 = c.z * H + d.z, p3 = c.w * H + d.w;
        unsigned int w0 = binpack[p0], w1 = binpack[p1];
        unsigned int w2 = binpack[p2], w3 = binpack[p3];

        cnt_inc(cnt_dst, a.x * H + b.x);
        cnt_inc(cnt_dst, a.y * H + b.y);
        cnt_inc(cnt_dst, a.z * H + b.z);
        cnt_inc(cnt_dst, a.w * H + b.w);

        const unsigned int ws2[4] = { w0, w1, w2, w3 };
        #pragma unroll
        for (int e = 0; e < 4; ++e) {
            unsigned int w = ws2[e];
            if (w == 0u) ++zc;
            else {
                atomicAdd(&hr[0 * BINS + (w & 0xFFu)], 1u);
                atomicAdd(&hr[1 * BINS + ((w >> 8) & 0xFFu)], 1u);
                atomicAdd(&hr[2 * BINS + ((w >> 16) & 0xFFu)], 1u);
            }
        }
    }

    int z = (int)zc;
    #pragma unroll
    for (int off = 32; off; off >>= 1) z += __shfl_down(z, off);
    if ((threadIdx.x & 63) == 0 && z) {
        atomicAdd(&hr[0 * BINS], (unsigned int)z);
        atomicAdd(&hr[1 * BINS], (unsigned int)z);
        atomicAdd(&hr[2 * BINS], (unsigned int)z);
    }

    __syncthreads();
    for (int i = threadIdx.x; i < CH * BINS; i += 256) {
        unsigned int v = hr[i];
        if (v) atomicAdd(&hist_ref[i], v);
    }
}

__global__ __launch_bounds__(256) void fb_sweep_kernel(
    const float* __restrict__ mask_src, const float* __restrict__ refimg,
    const unsigned int* __restrict__ cnt_dst,
    unsigned int* __restrict__ hist_dst)
{
    __shared__ unsigned int hd[CH * BINS];
    for (int i = threadIdx.x; i < CH * BINS; i += 256) hd[i] = 0u;
    __syncthreads();

    unsigned int zc = 0;
    const int nq = HH / 4;
    const int stride = gridDim.x * 256;
    for (int q = blockIdx.x * 256 + threadIdx.x; q < nq; q += stride) {
        uint2 wd = ((const uint2*)cnt_dst)[q];
        unsigned int cdc[4] = { wd.x & 0xFFFFu, wd.x >> 16, wd.y & 0xFFFFu, wd.y >> 16 };
        float4 ms4 = ((const float4*)mask_src)[q];
        const float ms[4] = { ms4.x, ms4.y, ms4.z, ms4.w };

        float rv[CH][4];
        #pragma unroll
        for (int c = 0; c < CH; ++c) {
            float4 r4 = ((const float4*)(refimg + (size_t)c * HH))[q];
            rv[c][0] = r4.x; rv[c][1] = r4.y; rv[c][2] = r4.z; rv[c][3] = r4.w;
        }
        #pragma unroll
        for (int e = 0; e < 4; ++e) {
            if (cdc[e]) {
                if (ms[e] == 0.0f) zc += cdc[e];
                else {
                    #pragma unroll
                    for (int c = 0; c < CH; ++c) {
                        float v = (rv[c][e] * 0.5f + 0.5f) * 255.0f;
                        atomicAdd(&hd[c * BINS + bin_of(v)], cdc[e]);
                    }
                }
            }
        }
    }

    int z = (int)zc;
    #pragma unroll
    for (int off = 32; off; off >>= 1) z += __shfl_down(z, off);
    if ((threadIdx.x & 63) == 0 && z) {
        atomicAdd(&hd[0 * BINS], (unsigned int)z);
        atomicAdd(&hd[1 * BINS], (unsigned int)z);
        atomicAdd(&hd[2 * BINS], (unsigned int)z);
    }

    __syncthreads();
    for (int i = threadIdx.x; i < CH * BINS; i += 256) {
        unsigned int v = hd[i];
        if (v) atomicAdd(&hist_dst[i], v);
    }
}

__global__ __launch_bounds__(256) void fb_loss_kernel(
    const float* __restrict__ input, const float* __restrict__ refimg,
    const float* __restrict__ mask_src, const unsigned int* __restrict__ cnt_dst,
    const int* __restrict__ table, double* __restrict__ acc)
{
    __shared__ int tab[CH * BINS];
    for (int i = threadIdx.x; i < CH * BINS; i += 256) tab[i] = table[i];
    __syncthreads();

    float lsum = 0.0f;
    const int nq = HH / 4;
    const int stride = gridDim.x * 256;
    for (int q = blockIdx.x * 256 + threadIdx.x; q < nq; q += stride) {
        float4 m4 = ((const float4*)mask_src)[q];
        uint2 w = ((const uint2*)cnt_dst)[q];
        const unsigned int sel[4] = { w.x & 0xFFFFu, w.x >> 16, w.y & 0xFFFFu, w.y >> 16 };
        const float mm[4] = { m4.x, m4.y, m4.z, m4.w };
        #pragma unroll
        for (int c = 0; c < CH; ++c) {
            float4 a4 = ((const float4*)(input + (size_t)c * HH))[q];
            float4 r4 = ((const float4*)(refimg + (size_t)c * HH))[q];
            const float aa[4] = { a4.x, a4.y, a4.z, a4.w };
            const float rr[4] = { r4.x, r4.y, r4.z, r4.w };
            #pragma unroll
            for (int e = 0; e < 4; ++e) {
                float m = mm[e];
                float av = (aa[e] * 0.5f + 0.5f) * 255.0f * m;
                float rv = (rr[e] * 0.5f + 0.5f) * 255.0f * m;
                float tv = (float)tab[c * BINS + bin_of(rv)];
                float mv = m * (sel[e] ? tv : rv);
                lsum += fabsf(av - mv);
            }
        }
    }

    double d = (double)lsum;
    #pragma unroll
    for (int off = 32; off; off >>= 1) d += __shfl_down(d, off);
    __shared__ double wsum[4];
    int wid = threadIdx.x >> 6;
    int lane = threadIdx.x & 63;
    if (lane == 0) wsum[wid] = d;
    __syncthreads();
    if (threadIdx.x == 0) {
        double t = wsum[0] + wsum[1] + wsum[2] + wsum[3];
        atomicAdd(acc, t);
    }
}

// ============================================================

extern "C" void kernel_launch(void* const* d_in, const int* in_sizes, int n_in,
                              void* d_out, int out_size, void* d_ws, size_t ws_size,
                              hipStream_t stream)
{
    const float* input    = (const float*)d_in[0];
    const float* target   = (const float*)d_in[1];
    const float* mask_src = (const float*)d_in[2];
    const float* mask_tar = (const float*)d_in[3];
    const int*   idx0     = (const int*)d_in[4];
    const int*   idx1     = (const int*)d_in[5];
    const int*   idx2     = (const int*)d_in[6];
    const int*   idx3     = (const int*)d_in[7];
    const float* refimg   = (const float*)d_in[8];

    char* ws = (char*)d_ws;
    unsigned int* hist_dst = (unsigned int*)(ws + WS_HIST_DST);
    unsigned int* hist_ref = (unsigned int*)(ws + WS_HIST_REF);
    int*          table    = (int*)(ws + WS_TABLE);
    double*       acc      = (double*)(ws + WS_ACC);

    if (ws_size >= WS_MAIN_BYTES) {
        unsigned int*   done_g   = (unsigned int*)(ws + WS_DONE_G);
        unsigned int*   done_l   = (unsigned int*)(ws + WS_DONE_L);
        unsigned char*  selected = (unsigned char*)(ws + WS_SEL);
        unsigned int*   bps      = (unsigned int*)(ws + WS_BPS);
        unsigned int*   bpr      = (unsigned int*)(ws + WS_BPR);
        unsigned int*   pd       = (unsigned int*)(ws + WS_PD);
        unsigned int*   pr       = (unsigned int*)(ws + WS_PR);

        // one contiguous memset: ctrl (hists/table/acc/tickets) + selected
        hipMemsetAsync(d_ws, 0, WS_ZERO_BYTES, stream);
        prep_pack_kernel<<<GRID1, 256, 0, stream>>>(
            mask_src, mask_tar, refimg, target, bps, bpr,
            idx0, idx1, idx2, idx3, pd, pr);
        scan_gather_kernel<<<SG_BLOCKS, 256, 0, stream>>>(pd, pr, bps, bpr,
                                                          selected, hist_dst, hist_ref,
                                                          table, done_g);
        loss_sel_kernel<<<L_BLOCKS, 256, 0, stream>>>(input, refimg, mask_src,
                                                      selected, table, acc,
                                                      (float*)d_out, done_l);
    } else {
        unsigned int* cnt_dst = (unsigned int*)(ws + FB_CNT_DST);
        unsigned int* binpack = (unsigned int*)(ws + FB_BINPACK);

        hipMemsetAsync(d_ws, 0, FB_ZERO_BYTES, stream);
        fb_prep_kernel<<<2048, 256, 0, stream>>>(mask_tar, target, binpack);
        fb_scatter_kernel<<<2048, 256, 0, stream>>>((const int4*)idx0, (const int4*)idx1,
                                                    (const int4*)idx2, (const int4*)idx3,
                                                    binpack, cnt_dst, hist_ref);
        fb_sweep_kernel<<<1024, 256, 0, stream>>>(mask_src, refimg, cnt_dst, hist_dst);
        table_kernel<<<1, 256, 0, stream>>>(hist_dst, hist_ref, table);
        fb_loss_kernel<<<2048, 256, 0, stream>>>(input, refimg, mask_src, cnt_dst,
                                                 table, acc);
        finalize_kernel<<<1, 64, 0, stream>>>(acc, (float*)d_out);
    }
}

// Round 8
// 290.653 us; speedup vs baseline: 1.1676x; 1.1676x over previous
//
#include <hip/hip_runtime.h>

#define H 2048
#define HH (H * H)
#define NIDX 2097152
#define BINS 256
#define CH 3

// ---------------- main-path ws layout ----------------
#define NLIST 128         // 2 sides x 64 buckets
#define CAPG  139264      // per-list capacity: mean 32768, big margin
#define WS_HIST_DST 0
#define WS_HIST_REF 3072
#define WS_TABLE    6144
#define WS_ACC      9216
#define WS_CURS     9728                        // uint[128], ends 10240
#define WS_DONE_G   10240                       // uint ticket (gather)
#define WS_DONE_L   10244                       // uint ticket (loss)
#define WS_CTRL_BYTES 16384
#define WS_SEL      16384                       // uchar[HH] (zeroed by prep)
#define WS_BPS      (16384 + (size_t)HH)        // uint[HH] binpack_src
#define WS_BPR      (WS_BPS + (size_t)HH * 4)   // uint[HH] binpack_ref
#define WS_LIST     (WS_BPR + (size_t)HH * 4)   // ushort[NLIST*CAPG]
#define WS_MAIN_BYTES (WS_LIST + (size_t)NLIST * CAPG * 2)

// ---------------- fallback ws layout ----------------
#define FB_CNT_DST  16384
#define FB_BINPACK  (16384 + (size_t)HH * 2)
#define FB_ZERO_BYTES (16384 + (size_t)HH * 2)

__device__ __forceinline__ int bin_of(float v) {
    int b = (int)floorf(v);
    return min(max(b, 0), BINS - 1);
}

// ============================================================
// MAIN PATH (R8 = R6 structure, banked; R7's scan variant REGRESSED:
// 8x redundant pd/pr stream = +150MB FETCH. Bucketed lists stay.)
// ============================================================
// Partition = R2 config (512 blocks, P1_CAP 96). R8 tweaks:
//  - wave-distributed writeback (4 waves x 32 lists, was 128 serial)
//  - sel zeroing folded into prep stores; memset shrunk to 16KB ctrl
// R3/R4 lesson: NO __threadfence() per block (L2 flush storm); tickets
// use device-scope atomics + __syncthreads drain only (R5-validated).
// R6 note: SQ_LDS_BANK_CONFLICT ~815K is summed over CUs (~3K cyc/CU),
// NOT a bottleneck — don't chase it.

#define P1_BLOCKS 512
#define P1_SPB (NIDX / P1_BLOCKS)   // 4096 samples/block
#define P1_CAP 96                   // per-list LDS capacity (mean fill 64)
#define PREP_BLOCKS 1024
#define PQ (HH / 4 / 4)             // 262144: prep far-split q-slice stride
#define FUSE_GRID (P1_BLOCKS + PREP_BLOCKS)

__global__ __launch_bounds__(256) void prep_part_kernel(
    // prep inputs/outputs
    const float* __restrict__ mask_src, const float* __restrict__ mask_tar,
    const float* __restrict__ refimg, const float* __restrict__ tgtimg,
    unsigned int* __restrict__ bps, unsigned int* __restrict__ bpr,
    unsigned int* __restrict__ sel4,
    // partition inputs/outputs
    const int* __restrict__ idx0, const int* __restrict__ idx1,
    const int* __restrict__ idx2, const int* __restrict__ idx3,
    unsigned short* __restrict__ list_g, unsigned int* __restrict__ curs)
{
    __shared__ unsigned short stage[NLIST * P1_CAP];   // 24 KB
    __shared__ unsigned int lcnt[NLIST];
    __shared__ unsigned int lbase[NLIST];

    if (blockIdx.x < P1_BLOCKS) {
        // ---------------- partition ----------------
        for (int i = threadIdx.x; i < NLIST; i += 256) lcnt[i] = 0u;
        __syncthreads();

        const int base4 = blockIdx.x * (P1_SPB / 4);   // int4 groups
        #pragma unroll
        for (int r = 0; r < P1_SPB / 1024; ++r) {      // 4 rounds
            int k4 = base4 + r * 256 + threadIdx.x;
            int4 a = ((const int4*)idx0)[k4];
            int4 b = ((const int4*)idx1)[k4];
            int4 c = ((const int4*)idx2)[k4];
            int4 d = ((const int4*)idx3)[k4];
            const int pd[4] = { a.x * H + b.x, a.y * H + b.y,
                                a.z * H + b.z, a.w * H + b.w };
            const int pr[4] = { c.x * H + d.x, c.y * H + d.y,
                                c.z * H + d.z, c.w * H + d.w };
            #pragma unroll
            for (int e = 0; e < 4; ++e) {
                {
                    int l = pd[e] >> 16;  // 0..63
                    unsigned int pos = atomicAdd(&lcnt[l], 1u);
                    if (pos < P1_CAP) stage[l * P1_CAP + pos] = (unsigned short)(pd[e] & 0xFFFF);
                    else {  // statistically ~impossible overflow slow path
                        unsigned int g = atomicAdd(&curs[l], 1u);
                        if (g < CAPG) list_g[(size_t)l * CAPG + g] = (unsigned short)(pd[e] & 0xFFFF);
                    }
                }
                {
                    int l = 64 + (pr[e] >> 16);
                    unsigned int pos = atomicAdd(&lcnt[l], 1u);
                    if (pos < P1_CAP) stage[l * P1_CAP + pos] = (unsigned short)(pr[e] & 0xFFFF);
                    else {
                        unsigned int g = atomicAdd(&curs[l], 1u);
                        if (g < CAPG) list_g[(size_t)l * CAPG + g] = (unsigned short)(pr[e] & 0xFFFF);
                    }
                }
            }
        }
        __syncthreads();
        if (threadIdx.x < NLIST) {
            unsigned int n = min(lcnt[threadIdx.x], (unsigned int)P1_CAP);
            lbase[threadIdx.x] = atomicAdd(&curs[threadIdx.x], n);
        }
        __syncthreads();
        // R8: wave-distributed writeback — 4 waves x 32 lists in parallel,
        // n<=96 over 64 lanes -> <=2 store rounds (was 128 serial iters).
        const int wave = threadIdx.x >> 6;
        const int lane = threadIdx.x & 63;
        for (int b = wave; b < NLIST; b += 4) {
            int n = (int)min(lcnt[b], (unsigned int)P1_CAP);
            unsigned int gb = lbase[b];
            for (int e = lane; e < n; e += 64) {
                unsigned int gi = gb + e;
                if (gi < CAPG) list_g[(size_t)b * CAPG + gi] = stage[b * P1_CAP + e];
            }
        }
    } else {
        // ---------------- prep: far-split 4-way, fully coalesced (R6) ----
        const int t = (int)(blockIdx.x - P1_BLOCKS) * 256 + threadIdx.x; // 0..262143
        float4 msv[4], mtv[4];
        #pragma unroll
        for (int k = 0; k < 4; ++k) {
            msv[k] = ((const float4*)mask_src)[t + k * PQ];
            mtv[k] = ((const float4*)mask_tar)[t + k * PQ];
        }
        unsigned int wsrc[4][4] = {{0u,0u,0u,0u},{0u,0u,0u,0u},{0u,0u,0u,0u},{0u,0u,0u,0u}};
        unsigned int wref[4][4] = {{0u,0u,0u,0u},{0u,0u,0u,0u},{0u,0u,0u,0u},{0u,0u,0u,0u}};
        #pragma unroll
        for (int c = 0; c < CH; ++c) {
            float4 rv[4], tv[4];
            #pragma unroll
            for (int k = 0; k < 4; ++k) {
                rv[k] = ((const float4*)(refimg + (size_t)c * HH))[t + k * PQ];
                tv[k] = ((const float4*)(tgtimg + (size_t)c * HH))[t + k * PQ];
            }
            #pragma unroll
            for (int k = 0; k < 4; ++k) {
                const float* rr = &rv[k].x;
                const float* tt = &tv[k].x;
                const float* mm = &msv[k].x;
                const float* mt2 = &mtv[k].x;
                #pragma unroll
                for (int e = 0; e < 4; ++e) {
                    float vs = (rr[e] * 0.5f + 0.5f) * 255.0f * mm[e];
                    float vt = (tt[e] * 0.5f + 0.5f) * 255.0f * mt2[e];
                    wsrc[k][e] |= ((unsigned int)bin_of(vs)) << (8 * c);
                    wref[k][e] |= ((unsigned int)bin_of(vt)) << (8 * c);
                }
            }
        }
        #pragma unroll
        for (int k = 0; k < 4; ++k) {
            uint4 os = { wsrc[k][0], wsrc[k][1], wsrc[k][2], wsrc[k][3] };
            uint4 orf = { wref[k][0], wref[k][1], wref[k][2], wref[k][3] };
            ((uint4*)bps)[t + k * PQ] = os;
            ((uint4*)bpr)[t + k * PQ] = orf;
            sel4[t + k * PQ] = 0u;              // R8: sel zeroing (was memset)
        }
    }
}

// XCD-localized gather (R0/R6): 1024 blocks = 8 xcd x 16 bucket-side x
// 8 sub; each thread processes batches of 8 list entries (one 16B list
// read -> 8 independent L2 gathers). Fence-free table tail (R5).
#define G_BLOCKS 1024
__global__ __launch_bounds__(256) void gather_hist_kernel(
    const unsigned short* __restrict__ list_g, const unsigned int* __restrict__ curs,
    const unsigned int* __restrict__ bps, const unsigned int* __restrict__ bpr,
    unsigned char* __restrict__ selected,
    unsigned int* __restrict__ hist_dst, unsigned int* __restrict__ hist_ref,
    int* __restrict__ table, unsigned int* __restrict__ done)
{
    __shared__ unsigned int hh[CH * BINS];
    for (int i = threadIdx.x; i < CH * BINS; i += 256) hh[i] = 0u;
    __syncthreads();

    const int xcd  = blockIdx.x & 7;
    const int j    = blockIdx.x >> 3;        // 0..127 within XCD
    const int bsl  = j & 15;                 // bucket-side local: 0..15
    const int sub  = j >> 4;                 // sub-range: 0..7
    const int side = bsl >> 3;               // 0 = dst, 1 = ref
    const int bucket = xcd * 8 + (bsl & 7);
    const int l = side * 64 + bucket;
    const unsigned int pbase = ((unsigned int)bucket) << 16;
    const unsigned int* __restrict__ src = side ? bpr : bps;

    const unsigned int n = min(curs[l], (unsigned int)CAPG);
    const unsigned int chunk = (((n + 7u) >> 3) + 7u) & ~7u;   // /8 subs, x8 align
    const unsigned int s = (unsigned int)sub * chunk;
    const unsigned int e = min(s + chunk, n);
    const unsigned short* lbase = list_g + (size_t)l * CAPG;

    unsigned int zc = 0;
    for (unsigned int ib = s + (unsigned int)threadIdx.x * 8u; ib < e; ib += 2048u) {
        unsigned int w[8];
        unsigned int pcnt;
        if (ib + 8u <= e) {
            uint4 raw = *(const uint4*)(lbase + ib);
            const unsigned int ent[8] = {
                raw.x & 0xFFFFu, raw.x >> 16, raw.y & 0xFFFFu, raw.y >> 16,
                raw.z & 0xFFFFu, raw.z >> 16, raw.w & 0xFFFFu, raw.w >> 16 };
            #pragma unroll
            for (int k = 0; k < 8; ++k) {
                unsigned int p = pbase | ent[k];
                w[k] = src[p];
                if (side == 0) selected[p] = 1;
            }
            pcnt = 8u;
        } else {
            pcnt = e - ib;
            #pragma unroll
            for (int k = 0; k < 8; ++k) {
                if ((unsigned int)k < pcnt) {
                    unsigned int p = pbase | (unsigned int)lbase[ib + k];
                    w[k] = src[p];
                    if (side == 0) selected[p] = 1;
                } else w[k] = 0xFFFFFFFFu;
            }
        }
        #pragma unroll
        for (int k = 0; k < 8; ++k) {
            if ((unsigned int)k < pcnt) {
                unsigned int ww = w[k];
                if (ww == 0u) ++zc;
                else {
                    atomicAdd(&hh[0 * BINS + (ww & 0xFFu)], 1u);
                    atomicAdd(&hh[1 * BINS + ((ww >> 8) & 0xFFu)], 1u);
                    atomicAdd(&hh[2 * BINS + ((ww >> 16) & 0xFFu)], 1u);
                }
            }
        }
    }

    int z = (int)zc;
    #pragma unroll
    for (int off = 32; off; off >>= 1) z += __shfl_down(z, off);
    if ((threadIdx.x & 63) == 0 && z) {
        atomicAdd(&hh[0 * BINS], (unsigned int)z);
        atomicAdd(&hh[1 * BINS], (unsigned int)z);
        atomicAdd(&hh[2 * BINS], (unsigned int)z);
    }

    __syncthreads();
    unsigned int* dsthist = side ? hist_ref : hist_dst;
    for (int i = threadIdx.x; i < CH * BINS; i += 256) {
        unsigned int v = hh[i];
        if (v) atomicAdd(&dsthist[i], v);
    }

    // ---- fence-free ticket: last block computes the table ----
    __shared__ int is_last;
    __syncthreads();                      // drains this block's vmem
    if (threadIdx.x == 0) {
        unsigned int t = atomicAdd(done, 1u);   // device-scope
        is_last = (t == gridDim.x - 1u) ? 1 : 0;
    }
    __syncthreads();
    if (!is_last) return;

    __shared__ float cd[CH * BINS];
    __shared__ float cr[CH * BINS];
    __shared__ float wpart[4];
    const int i = threadIdx.x;        // 0..255
    const int lane = i & 63;
    const int wave = i >> 6;

    for (int a = 0; a < 6; ++a) {
        unsigned int* h = (a < 3) ? (hist_dst + a * BINS) : (hist_ref + (a - 3) * BINS);
        float* out = (a < 3) ? (cd + a * BINS) : (cr + (a - 3) * BINS);
        // coherent read of device-scope atomic results: RMW with 0
        float x = (float)atomicAdd(&h[i], 0u);
        #pragma unroll
        for (int off = 1; off < 64; off <<= 1) {
            float y = __shfl_up(x, off);
            if (lane >= off) x += y;
        }
        if (lane == 63) wpart[wave] = x;
        __syncthreads();
        float prefix = 0.0f;
        #pragma unroll
        for (int w = 0; w < 3; ++w) if (w < wave) prefix += wpart[w];
        x += prefix;
        float tot = wpart[0] + wpart[1] + wpart[2] + wpart[3];
        out[i] = x / tot;
        __syncthreads();
    }

    #pragma unroll
    for (int c = 0; c < CH; ++c) {
        int t;
        if (i == 0) t = 0;
        else if (i == BINS - 1) t = BINS - 1;
        else {
            float r = cd[c * BINS + i];
            int lo = 1, hi = BINS - 1;
            while (lo < hi) {
                int mid = (lo + hi) >> 1;
                if (cr[c * BINS + mid] < r) lo = mid + 1; else hi = mid;
            }
            t = (cr[c * BINS + lo - 1] <= r) ? lo : i;
        }
        table[c * BINS + i] = t;
    }
}

// Far-split 4-way loss (grid 1024), fence-free fused finalize (R5/R6).
#define L_BLOCKS 1024
__global__ __launch_bounds__(256) void loss_sel_kernel(
    const float* __restrict__ input, const float* __restrict__ refimg,
    const float* __restrict__ mask_src, const unsigned char* __restrict__ selected,
    const int* __restrict__ table, double* __restrict__ acc,
    float* __restrict__ out_loss, unsigned int* __restrict__ done)
{
    __shared__ int tab[CH * BINS];
    for (int i = threadIdx.x; i < CH * BINS; i += 256) tab[i] = table[i];
    __syncthreads();

    const int t = blockIdx.x * 256 + threadIdx.x;   // 0..262143
    float4 mv[4];
    uchar4 sv[4];
    #pragma unroll
    for (int k = 0; k < 4; ++k) {
        mv[k] = ((const float4*)mask_src)[t + k * PQ];
        sv[k] = ((const uchar4*)selected)[t + k * PQ];
    }

    float lsum = 0.0f;
    #pragma unroll
    for (int c = 0; c < CH; ++c) {
        float4 av4[4], rv4[4];
        #pragma unroll
        for (int k = 0; k < 4; ++k) {
            av4[k] = ((const float4*)(input  + (size_t)c * HH))[t + k * PQ];
            rv4[k] = ((const float4*)(refimg + (size_t)c * HH))[t + k * PQ];
        }
        #pragma unroll
        for (int k = 0; k < 4; ++k) {
            const float* aa = &av4[k].x;
            const float* rr = &rv4[k].x;
            const float* mm = &mv[k].x;
            const unsigned char ss[4] = { sv[k].x, sv[k].y, sv[k].z, sv[k].w };
            #pragma unroll
            for (int e = 0; e < 4; ++e) {
                float m = mm[e];
                float av = (aa[e] * 0.5f + 0.5f) * 255.0f * m;
                float rv = (rr[e] * 0.5f + 0.5f) * 255.0f * m;
                float tv = (float)tab[c * BINS + bin_of(rv)];
                float mvv = m * (ss[e] ? tv : rv);
                lsum += fabsf(av - mvv);
            }
        }
    }

    double d = (double)lsum;
    #pragma unroll
    for (int off = 32; off; off >>= 1) d += __shfl_down(d, off);
    __shared__ double wsum[4];
    int wid = threadIdx.x >> 6;
    int lane = threadIdx.x & 63;
    if (lane == 0) wsum[wid] = d;
    __syncthreads();
    if (threadIdx.x == 0) {
        double tt = wsum[0] + wsum[1] + wsum[2] + wsum[3];
        atomicAdd(acc, tt);
    }

    // ---- fence-free ticket: last block writes the scalar output ----
    __shared__ int is_last;
    __syncthreads();
    if (threadIdx.x == 0) {
        unsigned int tk = atomicAdd(done, 1u);
        is_last = (tk == gridDim.x - 1u) ? 1 : 0;
    }
    __syncthreads();
    if (!is_last) return;
    if (threadIdx.x == 0) {
        double a = atomicAdd(acc, 0.0);   // coherent RMW read
        out_loss[0] = (float)(a / (double)(CH * (double)HH));
    }
}

// Standalone table/finalize kept for the fallback path.
__global__ __launch_bounds__(256) void table_kernel(
    const unsigned int* __restrict__ hist_dst,
    const unsigned int* __restrict__ hist_ref,
    int* __restrict__ table)
{
    __shared__ float cd[CH * BINS];
    __shared__ float cr[CH * BINS];
    __shared__ float wpart[4];
    const int i = threadIdx.x;        // 0..255
    const int lane = i & 63;
    const int wave = i >> 6;

    for (int a = 0; a < 6; ++a) {
        const unsigned int* h = (a < 3) ? (hist_dst + a * BINS) : (hist_ref + (a - 3) * BINS);
        float* out = (a < 3) ? (cd + a * BINS) : (cr + (a - 3) * BINS);
        float x = (float)h[i];
        #pragma unroll
        for (int off = 1; off < 64; off <<= 1) {
            float y = __shfl_up(x, off);
            if (lane >= off) x += y;
        }
        if (lane == 63) wpart[wave] = x;
        __syncthreads();
        float prefix = 0.0f;
        #pragma unroll
        for (int w = 0; w < 3; ++w) if (w < wave) prefix += wpart[w];
        x += prefix;
        float tot = wpart[0] + wpart[1] + wpart[2] + wpart[3];
        out[i] = x / tot;
        __syncthreads();
    }

    #pragma unroll
    for (int c = 0; c < CH; ++c) {
        int t;
        if (i == 0) t = 0;
        else if (i == BINS - 1) t = BINS - 1;
        else {
            float r = cd[c * BINS + i];
            int lo = 1, hi = BINS - 1;
            while (lo < hi) {
                int mid = (lo + hi) >> 1;
                if (cr[c * BINS + mid] < r) lo = mid + 1; else hi = mid;
            }
            t = (cr[c * BINS + lo - 1] <= r) ? lo : i;
        }
        table[c * BINS + i] = t;
    }
}

__global__ void finalize_kernel(const double* __restrict__ acc, float* __restrict__ out)
{
    if (threadIdx.x == 0 && blockIdx.x == 0) {
        out[0] = (float)(acc[0] / (double)(CH * (double)HH));
    }
}

// ============================================================
// FALLBACK PATH (proven pipeline) — used if ws_size too small
// ============================================================

__device__ __forceinline__ void cnt_inc(unsigned int* cnt, int p) {
    atomicAdd(&cnt[p >> 1], (p & 1) ? 0x10000u : 1u);
}

__global__ __launch_bounds__(256) void fb_prep_kernel(
    const float* __restrict__ mask_tar, const float* __restrict__ tgtimg,
    unsigned int* __restrict__ binpack)
{
    const int nq = HH / 4;
    const int stride = gridDim.x * 256;
    for (int q = blockIdx.x * 256 + threadIdx.x; q < nq; q += stride) {
        float4 m4 = ((const float4*)mask_tar)[q];
        const float mm[4] = { m4.x, m4.y, m4.z, m4.w };
        unsigned int w[4] = { 0u, 0u, 0u, 0u };
        #pragma unroll
        for (int c = 0; c < CH; ++c) {
            float4 t4 = ((const float4*)(tgtimg + (size_t)c * HH))[q];
            const float tt[4] = { t4.x, t4.y, t4.z, t4.w };
            #pragma unroll
            for (int e = 0; e < 4; ++e) {
                float v = (tt[e] * 0.5f + 0.5f) * 255.0f * mm[e];
                w[e] |= ((unsigned int)bin_of(v)) << (8 * c);
            }
        }
        uint4 out = { w[0], w[1], w[2], w[3] };
        ((uint4*)binpack)[q] = out;
    }
}

__global__ __launch_bounds__(256) void fb_scatter_kernel(
    const int4* __restrict__ idx0, const int4* __restrict__ idx1,
    const int4* __restrict__ idx2, const int4* __restrict__ idx3,
    const unsigned int* __restrict__ binpack,
    unsigned int* __restrict__ cnt_dst, unsigned int* __restrict__ hist_ref)
{
    __shared__ unsigned int hr[CH * BINS];
    for (int i = threadIdx.x; i < CH * BINS; i += 256) hr[i] = 0u;
    __syncthreads();

    unsigned int zc = 0;
    const int n4 = NIDX / 4;
    const int stride = gridDim.x * 256;
    for (int k = blockIdx.x * 256 + threadIdx.x; k < n4; k += stride) {
        int4 a = idx0[k], b = idx1[k], c = idx2[k], d = idx3[k];
        int p0 = c.x * H + d.x, p1 = c.y * H + d.y;
        int p2 = c.z * H + d.z, p3 = c.w * H + d.w;
        unsigned int w0 = binpack[p0], w1 = binpack[p1];
        unsigned int w2 = binpack[p2], w3 = binpack[p3];

        cnt_inc(cnt_dst, a.x * H + b.x);
        cnt_inc(cnt_dst, a.y * H + b.y);
        cnt_inc(cnt_dst, a.z * H + b.z);
        cnt_inc(cnt_dst, a.w * H + b.w);

        const unsigned int ws2[4] = { w0, w1, w2, w3 };
        #pragma unroll
        for (int e = 0; e < 4; ++e) {
            unsigned int w = ws2[e];
            if (w == 0u) ++zc;
            else {
                atomicAdd(&hr[0 * BINS + (w & 0xFFu)], 1u);
                atomicAdd(&hr[1 * BINS + ((w >> 8) & 0xFFu)], 1u);
                atomicAdd(&hr[2 * BINS + ((w >> 16) & 0xFFu)], 1u);
            }
        }
    }

    int z = (int)zc;
    #pragma unroll
    for (int off = 32; off; off >>= 1) z += __shfl_down(z, off);
    if ((threadIdx.x & 63) == 0 && z) {
        atomicAdd(&hr[0 * BINS], (unsigned int)z);
        atomicAdd(&hr[1 * BINS], (unsigned int)z);
        atomicAdd(&hr[2 * BINS], (unsigned int)z);
    }

    __syncthreads();
    for (int i = threadIdx.x; i < CH * BINS; i += 256) {
        unsigned int v = hr[i];
        if (v) atomicAdd(&hist_ref[i], v);
    }
}

__global__ __launch_bounds__(256) void fb_sweep_kernel(
    const float* __restrict__ mask_src, const float* __restrict__ refimg,
    const unsigned int* __restrict__ cnt_dst,
    unsigned int* __restrict__ hist_dst)
{
    __shared__ unsigned int hd[CH * BINS];
    for (int i = threadIdx.x; i < CH * BINS; i += 256) hd[i] = 0u;
    __syncthreads();

    unsigned int zc = 0;
    const int nq = HH / 4;
    const int stride = gridDim.x * 256;
    for (int q = blockIdx.x * 256 + threadIdx.x; q < nq; q += stride) {
        uint2 wd = ((const uint2*)cnt_dst)[q];
        unsigned int cdc[4] = { wd.x & 0xFFFFu, wd.x >> 16, wd.y & 0xFFFFu, wd.y >> 16 };
        float4 ms4 = ((const float4*)mask_src)[q];
        const float ms[4] = { ms4.x, ms4.y, ms4.z, ms4.w };

        float rv[CH][4];
        #pragma unroll
        for (int c = 0; c < CH; ++c) {
            float4 r4 = ((const float4*)(refimg + (size_t)c * HH))[q];
            rv[c][0] = r4.x; rv[c][1] = r4.y; rv[c][2] = r4.z; rv[c][3] = r4.w;
        }
        #pragma unroll
        for (int e = 0; e < 4; ++e) {
            if (cdc[e]) {
                if (ms[e] == 0.0f) zc += cdc[e];
                else {
                    #pragma unroll
                    for (int c = 0; c < CH; ++c) {
                        float v = (rv[c][e] * 0.5f + 0.5f) * 255.0f;
                        atomicAdd(&hd[c * BINS + bin_of(v)], cdc[e]);
                    }
                }
            }
        }
    }

    int z = (int)zc;
    #pragma unroll
    for (int off = 32; off; off >>= 1) z += __shfl_down(z, off);
    if ((threadIdx.x & 63) == 0 && z) {
        atomicAdd(&hd[0 * BINS], (unsigned int)z);
        atomicAdd(&hd[1 * BINS], (unsigned int)z);
        atomicAdd(&hd[2 * BINS], (unsigned int)z);
    }

    __syncthreads();
    for (int i = threadIdx.x; i < CH * BINS; i += 256) {
        unsigned int v = hd[i];
        if (v) atomicAdd(&hist_dst[i], v);
    }
}

__global__ __launch_bounds__(256) void fb_loss_kernel(
    const float* __restrict__ input, const float* __restrict__ refimg,
    const float* __restrict__ mask_src, const unsigned int* __restrict__ cnt_dst,
    const int* __restrict__ table, double* __restrict__ acc)
{
    __shared__ int tab[CH * BINS];
    for (int i = threadIdx.x; i < CH * BINS; i += 256) tab[i] = table[i];
    __syncthreads();

    float lsum = 0.0f;
    const int nq = HH / 4;
    const int stride = gridDim.x * 256;
    for (int q = blockIdx.x * 256 + threadIdx.x; q < nq; q += stride) {
        float4 m4 = ((const float4*)mask_src)[q];
        uint2 w = ((const uint2*)cnt_dst)[q];
        const unsigned int sel[4] = { w.x & 0xFFFFu, w.x >> 16, w.y & 0xFFFFu, w.y >> 16 };
        const float mm[4] = { m4.x, m4.y, m4.z, m4.w };
        #pragma unroll
        for (int c = 0; c < CH; ++c) {
            float4 a4 = ((const float4*)(input + (size_t)c * HH))[q];
            float4 r4 = ((const float4*)(refimg + (size_t)c * HH))[q];
            const float aa[4] = { a4.x, a4.y, a4.z, a4.w };
            const float rr[4] = { r4.x, r4.y, r4.z, r4.w };
            #pragma unroll
            for (int e = 0; e < 4; ++e) {
                float m = mm[e];
                float av = (aa[e] * 0.5f + 0.5f) * 255.0f * m;
                float rv = (rr[e] * 0.5f + 0.5f) * 255.0f * m;
                float tv = (float)tab[c * BINS + bin_of(rv)];
                float mv = m * (sel[e] ? tv : rv);
                lsum += fabsf(av - mv);
            }
        }
    }

    double d = (double)lsum;
    #pragma unroll
    for (int off = 32; off; off >>= 1) d += __shfl_down(d, off);
    __shared__ double wsum[4];
    int wid = threadIdx.x >> 6;
    int lane = threadIdx.x & 63;
    if (lane == 0) wsum[wid] = d;
    __syncthreads();
    if (threadIdx.x == 0) {
        double t = wsum[0] + wsum[1] + wsum[2] + wsum[3];
        atomicAdd(acc, t);
    }
}

// ============================================================

extern "C" void kernel_launch(void* const* d_in, const int* in_sizes, int n_in,
                              void* d_out, int out_size, void* d_ws, size_t ws_size,
                              hipStream_t stream)
{
    const float* input    = (const float*)d_in[0];
    const float* target   = (const float*)d_in[1];
    const float* mask_src = (const float*)d_in[2];
    const float* mask_tar = (const float*)d_in[3];
    const int*   idx0     = (const int*)d_in[4];
    const int*   idx1     = (const int*)d_in[5];
    const int*   idx2     = (const int*)d_in[6];
    const int*   idx3     = (const int*)d_in[7];
    const float* refimg   = (const float*)d_in[8];

    char* ws = (char*)d_ws;
    unsigned int* hist_dst = (unsigned int*)(ws + WS_HIST_DST);
    unsigned int* hist_ref = (unsigned int*)(ws + WS_HIST_REF);
    int*          table    = (int*)(ws + WS_TABLE);
    double*       acc      = (double*)(ws + WS_ACC);

    if (ws_size >= WS_MAIN_BYTES) {
        unsigned int*   curs     = (unsigned int*)(ws + WS_CURS);
        unsigned int*   done_g   = (unsigned int*)(ws + WS_DONE_G);
        unsigned int*   done_l   = (unsigned int*)(ws + WS_DONE_L);
        unsigned char*  selected = (unsigned char*)(ws + WS_SEL);
        unsigned int*   bps      = (unsigned int*)(ws + WS_BPS);
        unsigned int*   bpr      = (unsigned int*)(ws + WS_BPR);
        unsigned short* list_g   = (unsigned short*)(ws + WS_LIST);

        // ctrl-only memset (16KB); sel zeroed by prep stores
        hipMemsetAsync(d_ws, 0, WS_CTRL_BYTES, stream);
        prep_part_kernel<<<FUSE_GRID, 256, 0, stream>>>(
            mask_src, mask_tar, refimg, target, bps, bpr,
            (unsigned int*)selected,
            idx0, idx1, idx2, idx3, list_g, curs);
        gather_hist_kernel<<<G_BLOCKS, 256, 0, stream>>>(list_g, curs, bps, bpr,
                                                         selected, hist_dst, hist_ref,
                                                         table, done_g);
        loss_sel_kernel<<<L_BLOCKS, 256, 0, stream>>>(input, refimg, mask_src,
                                                      selected, table, acc,
                                                      (float*)d_out, done_l);
    } else {
        unsigned int* cnt_dst = (unsigned int*)(ws + FB_CNT_DST);
        unsigned int* binpack = (unsigned int*)(ws + FB_BINPACK);

        hipMemsetAsync(d_ws, 0, FB_ZERO_BYTES, stream);
        fb_prep_kernel<<<2048, 256, 0, stream>>>(mask_tar, target, binpack);
        fb_scatter_kernel<<<2048, 256, 0, stream>>>((const int4*)idx0, (const int4*)idx1,
                                                    (const int4*)idx2, (const int4*)idx3,
                                                    binpack, cnt_dst, hist_ref);
        fb_sweep_kernel<<<1024, 256, 0, stream>>>(mask_src, refimg, cnt_dst, hist_dst);
        table_kernel<<<1, 256, 0, stream>>>(hist_dst, hist_ref, table);
        fb_loss_kernel<<<2048, 256, 0, stream>>>(input, refimg, mask_src, cnt_dst,
                                                 table, acc);
        finalize_kernel<<<1, 64, 0, stream>>>(acc, (float*)d_out);
    }
}